// Round 6
// baseline (386.689 us; speedup 1.0000x reference)
//
#include <hip/hip_runtime.h>

// DigitCaps on MI355X, fp32 I/O, R6.
// R2: fp32 atomicAdd = CAS loop -> native int atomics only (LDS).
// R3: seg accumulators overflow int32 at scale 2^17 (winner-biased sums ~3e5).
// R4: VGPR 220 -> 2 waves/SIMD latency-bound; deep global atomic trees hide a tail.
// R5: 590K contended global u64 atomics (1024 addrs x 576 deep) = 50us tail +
//     184MB FETCH / 150MB WRITE of coherence-point RMW traffic.
// R6: ZERO global atomics. votes -> plain per-block partial stores (coalesced);
//     reduce kernel (17 blocks, coalesced column sums) -> s_final/seg_final;
//     final kernel (1 block) -> dc_new + output GEMV. No memset needed.
//
// Sizes: B=128, J=4608, INPUT_D=8, D=8, M=4 -> N=18432 votes, C=10.
// Output = concat(output[128,10], digit_caps_new[10,8]).
// Math: output[b,c] = <(1/N) sum_n u[b,n], dc_new[c]> -> only s[b,:] needed.
// Vote n=j*4+m has components u[b,j,m*8+d].
//
// ws layout (4B units):
//   [0, 110592)        part_seg int32 [1152][96]  (cols: c*9+d, d==8 -> count)
//   [110592, 700416)   part_s  float [1152][512]  (col = bl*8+d, b = h*64+bl)
//   [700416, 701440)   s_final float [1024]
//   i64 units [350720, 350810)  seg_final long long [90]

#define J_POS 4608
#define WSTRIDE 264         // 256+8 pad: 8 distinct W addrs/wave, 2-way bank alias = free
#define SEGSTRIDE 97        // 97%32=1 -> replica r shifts banks by r
#define NREP 16
#define NVOTES 18432.0f
#define DENOM  2359296.0f   // B*N
#define SEG_SCALE 32768.0f  // 2^15: per-replica block sums < 2^31 with margin
#define INV_SEG_SCALE 3.0517578125e-5f
#define OFF_PART_S   110592
#define OFF_S_FINAL  700416
#define OFF_SEG_FINAL_LL 350720

__global__ __launch_bounds__(256, 4) void votes_kernel(
    const float* __restrict__ x,   // [B, J, 8]
    const float* __restrict__ w,   // [J, 8, 32]
    const float* __restrict__ dc,  // [10, 8]
    int* __restrict__ part_seg,
    float* __restrict__ part_s)
{
    __shared__ float w_lds[8 * WSTRIDE];
    __shared__ __align__(16) float dc_lds[80];
    __shared__ int seg_lds[NREP * SEGSTRIDE];
    __shared__ float s_lds[64 * 8];

    const int t  = threadIdx.x;
    const int jg = blockIdx.x >> 1;
    const int h  = blockIdx.x & 1;      // batch half
    const int j0 = jg * 8;

    // ---- stage W tile: 8 j * 256 floats; thread t loads 8 floats
    {
        const int idx = t * 8;
        const int jj = idx >> 8, rem = idx & 255;
        const float4 r0 = *(const float4*)(w + (size_t)j0 * 256 + idx);
        const float4 r1 = *(const float4*)(w + (size_t)j0 * 256 + idx + 4);
        float* dst = &w_lds[jj * WSTRIDE + rem];
        dst[0] = r0.x; dst[1] = r0.y; dst[2] = r0.z; dst[3] = r0.w;
        dst[4] = r1.x; dst[5] = r1.y; dst[6] = r1.z; dst[7] = r1.w;
    }
    if (t < 80) dc_lds[t] = dc[t];
    for (int i = t; i < NREP * SEGSTRIDE; i += 256) seg_lds[i] = 0;
    __syncthreads();

    const int jj   = t & 7;        // consecutive lanes -> consecutive j
    const int brow = t >> 3;       // 0..31
    const int b1 = h * 64 + brow, b2 = b1 + 32;
    int* const segp = &seg_lds[((t >> 2) & (NREP - 1)) * SEGSTRIDE]; // 4 lanes/replica

    const float* xp1 = x + ((size_t)b1 * J_POS + j0 + jj) * 8;
    const float* xp2 = x + ((size_t)b2 * J_POS + j0 + jj) * 8;
    const float4 a0 = *(const float4*)xp1, a1 = *(const float4*)(xp1 + 4);
    const float4 c0 = *(const float4*)xp2, c1 = *(const float4*)(xp2 + 4);
    const float xf1[8] = {a0.x,a0.y,a0.z,a0.w,a1.x,a1.y,a1.z,a1.w};
    const float xf2[8] = {c0.x,c0.y,c0.z,c0.w,c1.x,c1.y,c1.z,c1.w};

    float su1[8] = {0,0,0,0,0,0,0,0};
    float su2[8] = {0,0,0,0,0,0,0,0};
    const float* wbase = &w_lds[jj * WSTRIDE];

    #pragma unroll 1               // 2 votes (m=2p,2p+1) per pass: dc reads halved
    for (int p = 0; p < 2; ++p) {
        float ua1[8]={0,0,0,0,0,0,0,0}, ub1[8]={0,0,0,0,0,0,0,0};  // row1: m0, m1
        float ua2[8]={0,0,0,0,0,0,0,0}, ub2[8]={0,0,0,0,0,0,0,0};  // row2: m0, m1
        #pragma unroll
        for (int i = 0; i < 8; ++i) {
            // W cols [16p,16p+16): 16 contiguous floats (m0 d0..7, m1 d0..7)
            const float4 w0 = *(const float4*)(wbase + i * 32 + p * 16);
            const float4 w1 = *(const float4*)(wbase + i * 32 + p * 16 + 4);
            const float4 w2 = *(const float4*)(wbase + i * 32 + p * 16 + 8);
            const float4 w3 = *(const float4*)(wbase + i * 32 + p * 16 + 12);
            const float x1 = xf1[i], x2 = xf2[i];
            ua1[0]+=x1*w0.x; ua1[1]+=x1*w0.y; ua1[2]+=x1*w0.z; ua1[3]+=x1*w0.w;
            ua1[4]+=x1*w1.x; ua1[5]+=x1*w1.y; ua1[6]+=x1*w1.z; ua1[7]+=x1*w1.w;
            ub1[0]+=x1*w2.x; ub1[1]+=x1*w2.y; ub1[2]+=x1*w2.z; ub1[3]+=x1*w2.w;
            ub1[4]+=x1*w3.x; ub1[5]+=x1*w3.y; ub1[6]+=x1*w3.z; ub1[7]+=x1*w3.w;
            ua2[0]+=x2*w0.x; ua2[1]+=x2*w0.y; ua2[2]+=x2*w0.z; ua2[3]+=x2*w0.w;
            ua2[4]+=x2*w1.x; ua2[5]+=x2*w1.y; ua2[6]+=x2*w1.z; ua2[7]+=x2*w1.w;
            ub2[0]+=x2*w2.x; ub2[1]+=x2*w2.y; ub2[2]+=x2*w2.z; ub2[3]+=x2*w2.w;
            ub2[4]+=x2*w3.x; ub2[5]+=x2*w3.y; ub2[6]+=x2*w3.z; ub2[7]+=x2*w3.w;
        }

        // ---- argmax over 10 caps for 4 votes; dc read broadcast (wave-uniform)
        float bs_a1=-3.402823466e38f, bs_b1=bs_a1, bs_a2=bs_a1, bs_b2=bs_a1;
        int bc_a1=0, bc_b1=0, bc_a2=0, bc_b2=0;
        #pragma unroll
        for (int c = 0; c < 10; ++c) {
            const float4 da = *(const float4*)&dc_lds[c * 8];
            const float4 db = *(const float4*)&dc_lds[c * 8 + 4];
            const float sa1 = ua1[0]*da.x+ua1[1]*da.y+ua1[2]*da.z+ua1[3]*da.w
                            + ua1[4]*db.x+ua1[5]*db.y+ua1[6]*db.z+ua1[7]*db.w;
            const float sb1 = ub1[0]*da.x+ub1[1]*da.y+ub1[2]*da.z+ub1[3]*da.w
                            + ub1[4]*db.x+ub1[5]*db.y+ub1[6]*db.z+ub1[7]*db.w;
            const float sa2 = ua2[0]*da.x+ua2[1]*da.y+ua2[2]*da.z+ua2[3]*da.w
                            + ua2[4]*db.x+ua2[5]*db.y+ua2[6]*db.z+ua2[7]*db.w;
            const float sb2 = ub2[0]*da.x+ub2[1]*da.y+ub2[2]*da.z+ub2[3]*da.w
                            + ub2[4]*db.x+ub2[5]*db.y+ub2[6]*db.z+ub2[7]*db.w;
            if (sa1 > bs_a1) { bs_a1 = sa1; bc_a1 = c; }   // strict > = first max
            if (sb1 > bs_b1) { bs_b1 = sb1; bc_b1 = c; }
            if (sa2 > bs_a2) { bs_a2 = sa2; bc_a2 = c; }
            if (sb2 > bs_b2) { bs_b2 = sb2; bc_b2 = c; }
        }

        // ---- native int LDS atomics, fire-and-forget
        const int oa1 = bc_a1 * 9, ob1 = bc_b1 * 9, oa2 = bc_a2 * 9, ob2 = bc_b2 * 9;
        #pragma unroll
        for (int d = 0; d < 8; ++d) {
            atomicAdd(&segp[oa1 + d], __float2int_rn(ua1[d] * SEG_SCALE));
            atomicAdd(&segp[ob1 + d], __float2int_rn(ub1[d] * SEG_SCALE));
            atomicAdd(&segp[oa2 + d], __float2int_rn(ua2[d] * SEG_SCALE));
            atomicAdd(&segp[ob2 + d], __float2int_rn(ub2[d] * SEG_SCALE));
        }
        atomicAdd(&segp[oa1 + 8], 1); atomicAdd(&segp[ob1 + 8], 1);
        atomicAdd(&segp[oa2 + 8], 1); atomicAdd(&segp[ob2 + 8], 1);

        #pragma unroll
        for (int d = 0; d < 8; ++d) {
            su1[d] += ua1[d] + ub1[d];
            su2[d] += ua2[d] + ub2[d];
        }
    }

    // ---- reduce su across the 8 jj-lanes (same wave)
    #pragma unroll
    for (int d = 0; d < 8; ++d) {
        su1[d] += __shfl_xor(su1[d], 1);
        su1[d] += __shfl_xor(su1[d], 2);
        su1[d] += __shfl_xor(su1[d], 4);
        su2[d] += __shfl_xor(su2[d], 1);
        su2[d] += __shfl_xor(su2[d], 2);
        su2[d] += __shfl_xor(su2[d], 4);
    }
    if (jj == 0) {
        #pragma unroll
        for (int d = 0; d < 8; ++d) {
            s_lds[brow * 8 + d] = su1[d];
            s_lds[(brow + 32) * 8 + d] = su2[d];
        }
    }
    __syncthreads();

    // ---- flush partials: plain coalesced stores, zero global atomics
    if (t < 90) {
        int v = 0;
        #pragma unroll
        for (int r = 0; r < NREP; ++r) v += seg_lds[r * SEGSTRIDE + t];
        part_seg[blockIdx.x * 96 + t] = v;
    }
    *(float2*)&part_s[(size_t)blockIdx.x * 512 + t * 2] = *(const float2*)&s_lds[t * 2];
}

// blocks 0..15: s column-reduce (coalesced); block 16: seg column-reduce
__global__ __launch_bounds__(256) void reduce_kernel(
    const int* __restrict__ part_seg,
    const float* __restrict__ part_s,
    float* __restrict__ s_final,
    long long* __restrict__ seg_final)
{
    const int t = threadIdx.x;
    if (blockIdx.x < 16) {
        __shared__ float red[64][5];        // pad to 5 -> no bank conflict on re-read
        const int g0 = blockIdx.x * 64;
        const int h = g0 >> 9;
        const int gl = t & 63, chunk = t >> 6;
        const int col = (g0 + gl) & 511;
        float acc = 0.f;
        #pragma unroll 8
        for (int i = chunk * 144; i < chunk * 144 + 144; ++i)
            acc += part_s[(size_t)(2 * i + h) * 512 + col];
        red[gl][chunk] = acc;
        __syncthreads();
        if (t < 64) s_final[g0 + t] = red[t][0] + red[t][1] + red[t][2] + red[t][3];
    } else {
        __shared__ long long segred[2][96];
        const int o = t % 96, r = t / 96;
        if (t < 192) {
            long long acc = 0;
            if (o < 90) {
                #pragma unroll 8
                for (int i = 0; i < 576; ++i)
                    acc += part_seg[(r * 576 + i) * 96 + o];
            }
            segred[r][o] = acc;
        }
        __syncthreads();
        if (t < 90) seg_final[t] = segred[0][t] + segred[1][t];
    }
}

__global__ __launch_bounds__(256) void final_kernel(
    const float* __restrict__ s_final,
    const long long* __restrict__ seg_final,
    const float* __restrict__ dc,
    float* __restrict__ out)       // [0,1280): output  [1280,1360): dc_new
{
    __shared__ float dcn[80];
    __shared__ float sf[1024];
    const int t = threadIdx.x;

    if (t < 80) {
        const int c = t >> 3, d = t & 7;
        const float segf = (float)seg_final[c * 9 + d] * INV_SEG_SCALE;
        const float cntf = (float)seg_final[c * 9 + 8];
        const float d0 = dc[t];
        const float nd = d0 + (segf - cntf * d0) * (1.0f / DENOM);
        dcn[t] = nd;
        out[1280 + t] = nd;
    }
    #pragma unroll
    for (int r = 0; r < 4; ++r) {
        const int i = r * 256 + t;
        sf[i] = s_final[i] * (1.0f / NVOTES);
    }
    __syncthreads();

    #pragma unroll
    for (int r = 0; r < 5; ++r) {
        const int idx = r * 256 + t;        // 0..1279
        const int b = idx / 10, c = idx - b * 10;
        float acc = 0.f;
        #pragma unroll
        for (int d = 0; d < 8; ++d) acc += sf[b * 8 + d] * dcn[c * 8 + d];
        out[idx] = acc;
    }
}

extern "C" void kernel_launch(void* const* d_in, const int* in_sizes, int n_in,
                              void* d_out, int out_size, void* d_ws, size_t ws_size,
                              hipStream_t stream) {
    const float* x  = (const float*)d_in[0];
    const float* w  = (const float*)d_in[1];
    const float* dc = (const float*)d_in[2];
    float* out = (float*)d_out;
    int*       part_seg  = (int*)d_ws;
    float*     part_s    = (float*)d_ws + OFF_PART_S;
    float*     s_final   = (float*)d_ws + OFF_S_FINAL;
    long long* seg_final = (long long*)d_ws + OFF_SEG_FINAL_LL;

    votes_kernel<<<1152, 256, 0, stream>>>(x, w, dc, part_seg, part_s);
    reduce_kernel<<<17, 256, 0, stream>>>(part_seg, part_s, s_final, seg_final);
    final_kernel<<<1, 256, 0, stream>>>(s_final, seg_final, dc, out);
}

// Round 7
// 164.076 us; speedup vs baseline: 2.3568x; 2.3568x over previous
//
#include <hip/hip_runtime.h>

// DigitCaps on MI355X, fp32 I/O, R7.
// R2: fp32 atomicAdd = CAS loop -> native int atomics only (LDS).
// R3: seg accumulators are winner-biased (~3e5) -> int64 finals.
// R5: deep same-address global atomic trees = coherence-point RMW storm.
// R6: 80 live floats in the i-loop at forced 64 VGPR -> 485MB scratch spill
//     (WRITE_SIZE is the spill detector; useful writes are ~3MB).
// R7: R5's verified 48-float inner loop + plain-store partial flush; reduce
//     and final merged into ONE kernel via last-done-block (device-scope
//     atomic counter + agent-scope atomic loads/stores for partials).
//     ~60us of the previous totals was per-dispatch overhead (constant tail
//     across R2/R4/R5/R6) -> 2 dispatches instead of 4.
//
// Sizes: B=128, J=4608, INPUT_D=8, D=8, M=4 -> N=18432 votes, C=10.
// Output = concat(output[128,10], digit_caps_new[10,8]).
// Math: output[b,c] = <(1/N) sum_n u[b,n], dc_new[c]> -> only s[b,:] needed.
//
// ws layout (4B units):
//   [0]                 done counter
//   [64, 110656)        part_seg int [1152][96] (col c*9+d; d==8 -> count)
//   [110656, 700480)    part_s float [1152][512] (col = local_b*8+d)
//   [700480, 701504)    s_final float [1024]
//   ll units [350752, 351136)  seg_part long long [4][96]

#define J_POS 4608
#define WSTRIDE 264         // 256+8 pad: 8 distinct W addrs/wave, 2-way alias = free
#define SEGSTRIDE 97        // 97%32=1 -> replica r shifts banks by r
#define NREP 16
#define NVOTES 18432.0f
#define DENOM  2359296.0f   // B*N
#define SEG_SCALE 32768.0f  // 2^15
#define INV_SEG_SCALE 3.0517578125e-5f
#define OFF_PART_SEG 64
#define OFF_PART_S   110656
#define OFF_S_FINAL  700480
#define OFF_SEG_PART_LL 350752

__global__ __launch_bounds__(256, 4) void votes_kernel(
    const float* __restrict__ x,   // [B, J, 8]
    const float* __restrict__ w,   // [J, 8, 32]
    const float* __restrict__ dc,  // [10, 8]
    int* __restrict__ part_seg,
    float* __restrict__ part_s,
    int* __restrict__ done)
{
    __shared__ float w_lds[8 * WSTRIDE];
    __shared__ __align__(16) float dc_lds[80];
    __shared__ int seg_lds[NREP * SEGSTRIDE];
    __shared__ float s_lds[64 * 8];

    const int t  = threadIdx.x;
    const int jg = blockIdx.x >> 1;
    const int h  = blockIdx.x & 1;      // batch half
    const int j0 = jg * 8;

    if (blockIdx.x == 0 && t == 0) *done = 0;   // reduce launches after us (stream order)

    // ---- stage W tile: 8 j * 256 floats; thread t loads 8 floats
    {
        const int idx = t * 8;
        const int jj = idx >> 8, rem = idx & 255;
        const float4 r0 = *(const float4*)(w + (size_t)j0 * 256 + idx);
        const float4 r1 = *(const float4*)(w + (size_t)j0 * 256 + idx + 4);
        float* dst = &w_lds[jj * WSTRIDE + rem];
        dst[0] = r0.x; dst[1] = r0.y; dst[2] = r0.z; dst[3] = r0.w;
        dst[4] = r1.x; dst[5] = r1.y; dst[6] = r1.z; dst[7] = r1.w;
    }
    if (t < 80) dc_lds[t] = dc[t];
    for (int i = t; i < NREP * SEGSTRIDE; i += 256) seg_lds[i] = 0;
    __syncthreads();

    const int jj   = t & 7;        // consecutive lanes -> consecutive j (coalesced x)
    const int brow = t >> 3;       // 0..31
    const int b1 = h * 64 + brow, b2 = b1 + 32;
    int* const segp = &seg_lds[((t >> 2) & (NREP - 1)) * SEGSTRIDE];

    const float* xp1 = x + ((size_t)b1 * J_POS + j0 + jj) * 8;
    const float* xp2 = x + ((size_t)b2 * J_POS + j0 + jj) * 8;
    const float4 a0 = *(const float4*)xp1, a1 = *(const float4*)(xp1 + 4);
    const float4 c0 = *(const float4*)xp2, c1 = *(const float4*)(xp2 + 4);
    const float xf1[8] = {a0.x,a0.y,a0.z,a0.w,a1.x,a1.y,a1.z,a1.w};
    const float xf2[8] = {c0.x,c0.y,c0.z,c0.w,c1.x,c1.y,c1.z,c1.w};

    float su1[8] = {0,0,0,0,0,0,0,0};
    float su2[8] = {0,0,0,0,0,0,0,0};
    const float* wbase = &w_lds[jj * WSTRIDE];

    #pragma unroll 1               // ONE vote-column pair at a time: 48 live floats, no spill
    for (int m = 0; m < 4; ++m) {
        float u1[8] = {0,0,0,0,0,0,0,0};
        float u2[8] = {0,0,0,0,0,0,0,0};
        #pragma unroll
        for (int i = 0; i < 8; ++i) {
            const float4 wa = *(const float4*)(wbase + i * 32 + m * 8);
            const float4 wb = *(const float4*)(wbase + i * 32 + m * 8 + 4);
            const float x1 = xf1[i], x2 = xf2[i];
            u1[0] += x1*wa.x; u1[1] += x1*wa.y; u1[2] += x1*wa.z; u1[3] += x1*wa.w;
            u1[4] += x1*wb.x; u1[5] += x1*wb.y; u1[6] += x1*wb.z; u1[7] += x1*wb.w;
            u2[0] += x2*wa.x; u2[1] += x2*wa.y; u2[2] += x2*wa.z; u2[3] += x2*wa.w;
            u2[4] += x2*wb.x; u2[5] += x2*wb.y; u2[6] += x2*wb.z; u2[7] += x2*wb.w;
        }

        // ---- argmax over 10 caps; dc read as wave-uniform broadcast (free)
        float best1 = -3.402823466e38f, best2 = -3.402823466e38f;
        int bc1 = 0, bc2 = 0;
        #pragma unroll
        for (int c = 0; c < 10; ++c) {
            const float4 da = *(const float4*)&dc_lds[c * 8];
            const float4 db = *(const float4*)&dc_lds[c * 8 + 4];
            const float s1 = u1[0]*da.x + u1[1]*da.y + u1[2]*da.z + u1[3]*da.w
                           + u1[4]*db.x + u1[5]*db.y + u1[6]*db.z + u1[7]*db.w;
            const float s2 = u2[0]*da.x + u2[1]*da.y + u2[2]*da.z + u2[3]*da.w
                           + u2[4]*db.x + u2[5]*db.y + u2[6]*db.z + u2[7]*db.w;
            if (s1 > best1) { best1 = s1; bc1 = c; }   // strict > = first max (jnp)
            if (s2 > best2) { best2 = s2; bc2 = c; }
        }

        // ---- native int LDS atomics, fire-and-forget
        const int o1 = bc1 * 9, o2 = bc2 * 9;
        #pragma unroll
        for (int d = 0; d < 8; ++d)
            atomicAdd(&segp[o1 + d], __float2int_rn(u1[d] * SEG_SCALE));
        atomicAdd(&segp[o1 + 8], 1);
        #pragma unroll
        for (int d = 0; d < 8; ++d)
            atomicAdd(&segp[o2 + d], __float2int_rn(u2[d] * SEG_SCALE));
        atomicAdd(&segp[o2 + 8], 1);

        #pragma unroll
        for (int d = 0; d < 8; ++d) { su1[d] += u1[d]; su2[d] += u2[d]; }
    }

    // ---- reduce su across the 8 jj-lanes (same wave)
    #pragma unroll
    for (int d = 0; d < 8; ++d) {
        su1[d] += __shfl_xor(su1[d], 1);
        su1[d] += __shfl_xor(su1[d], 2);
        su1[d] += __shfl_xor(su1[d], 4);
        su2[d] += __shfl_xor(su2[d], 1);
        su2[d] += __shfl_xor(su2[d], 2);
        su2[d] += __shfl_xor(su2[d], 4);
    }
    if (jj == 0) {
        #pragma unroll
        for (int d = 0; d < 8; ++d) {
            s_lds[brow * 8 + d] = su1[d];
            s_lds[(brow + 32) * 8 + d] = su2[d];
        }
    }
    __syncthreads();

    // ---- flush partials: plain coalesced stores, ZERO global atomics
    if (t < 90) {
        int v = 0;
        #pragma unroll
        for (int r = 0; r < NREP; ++r) v += seg_lds[r * SEGSTRIDE + t];
        part_seg[blockIdx.x * 96 + t] = v;
    }
    *(float2*)&part_s[(size_t)blockIdx.x * 512 + t * 2] = *(const float2*)&s_lds[t * 2];
}

// 20 blocks: 0..15 s-columns, 16..19 seg-quarters; last-done block runs the final.
__global__ __launch_bounds__(256) void reduce_final_kernel(
    const int* __restrict__ part_seg,
    const float* __restrict__ part_s,
    float* __restrict__ s_final,
    long long* __restrict__ seg_part,
    int* __restrict__ done,
    const float* __restrict__ dc,
    float* __restrict__ out)       // [0,1280): output  [1280,1360): dc_new
{
    __shared__ float red[64][5];
    __shared__ long long segred[2][96];
    __shared__ float dcn[80];
    __shared__ float sf[1024];
    __shared__ int lastflag;

    const int t = threadIdx.x;
    const int bid = blockIdx.x;

    if (bid < 16) {
        // ---- s column-reduce: 64 cols, 4 chunks of 144 rows (parity h)
        const int g0 = bid * 64;
        const int h = g0 >> 9;
        const int gl = t & 63, chunk = t >> 6;
        const int col = (g0 + gl) & 511;
        float acc = 0.f;
        #pragma unroll 8
        for (int i = chunk * 144; i < chunk * 144 + 144; ++i)
            acc += part_s[(size_t)(2 * i + h) * 512 + col];
        red[gl][chunk] = acc;
        __syncthreads();
        if (t < 64)
            __hip_atomic_store(&s_final[g0 + t],
                               red[t][0] + red[t][1] + red[t][2] + red[t][3],
                               __ATOMIC_RELAXED, __HIP_MEMORY_SCOPE_AGENT);
    } else {
        // ---- seg quarter-reduce: 288 rows, 96 cols, 2 row-chunks
        const int p = bid - 16;
        if (t < 192) {
            const int o = t % 96, rc = t / 96;
            long long acc = 0;
            const int r0 = p * 288 + rc * 144;
            #pragma unroll 8
            for (int i = r0; i < r0 + 144; ++i)
                acc += part_seg[(size_t)i * 96 + o];
            segred[rc][o] = acc;
        }
        __syncthreads();
        if (t < 96)
            __hip_atomic_store(&seg_part[p * 96 + t], segred[0][t] + segred[1][t],
                               __ATOMIC_RELAXED, __HIP_MEMORY_SCOPE_AGENT);
    }

    // ---- completion protocol: release stores, count blocks, last one finalizes
    __threadfence();
    __syncthreads();
    if (t == 0) lastflag = (atomicAdd(done, 1) == 19) ? 1 : 0;
    __syncthreads();
    if (!lastflag) return;
    __threadfence();

    // ---- final (one block): dc_new + output GEMV; agent-scope loads of partials
    #pragma unroll
    for (int r = 0; r < 4; ++r) {
        const int i = r * 256 + t;
        const float v = __hip_atomic_load(&s_final[i], __ATOMIC_RELAXED,
                                          __HIP_MEMORY_SCOPE_AGENT);
        sf[i] = v * (1.0f / NVOTES);
    }
    if (t < 80) {
        const int c = t >> 3, d = t & 7;
        long long sv = 0, cv = 0;
        #pragma unroll
        for (int p = 0; p < 4; ++p) {
            sv += __hip_atomic_load(&seg_part[p * 96 + c * 9 + d], __ATOMIC_RELAXED,
                                    __HIP_MEMORY_SCOPE_AGENT);
            cv += __hip_atomic_load(&seg_part[p * 96 + c * 9 + 8], __ATOMIC_RELAXED,
                                    __HIP_MEMORY_SCOPE_AGENT);
        }
        const float d0 = dc[t];
        const float nd = d0 + ((float)sv * INV_SEG_SCALE - (float)cv * d0) * (1.0f / DENOM);
        dcn[t] = nd;
        out[1280 + t] = nd;
    }
    __syncthreads();

    #pragma unroll
    for (int r = 0; r < 5; ++r) {
        const int idx = r * 256 + t;        // 0..1279
        const int b = idx / 10, c = idx - b * 10;
        float acc = 0.f;
        #pragma unroll
        for (int d = 0; d < 8; ++d) acc += sf[b * 8 + d] * dcn[c * 8 + d];
        out[idx] = acc;
    }
}

extern "C" void kernel_launch(void* const* d_in, const int* in_sizes, int n_in,
                              void* d_out, int out_size, void* d_ws, size_t ws_size,
                              hipStream_t stream) {
    const float* x  = (const float*)d_in[0];
    const float* w  = (const float*)d_in[1];
    const float* dc = (const float*)d_in[2];
    float* out = (float*)d_out;
    int*       done      = (int*)d_ws;
    int*       part_seg  = (int*)d_ws + OFF_PART_SEG;
    float*     part_s    = (float*)d_ws + OFF_PART_S;
    float*     s_final   = (float*)d_ws + OFF_S_FINAL;
    long long* seg_part  = (long long*)d_ws + OFF_SEG_PART_LL;

    votes_kernel<<<1152, 256, 0, stream>>>(x, w, dc, part_seg, part_s, done);
    reduce_final_kernel<<<20, 256, 0, stream>>>(part_seg, part_s, s_final,
                                                seg_part, done, dc, out);
}